// Round 4
// baseline (162.585 us; speedup 1.0000x reference)
//
#include <hip/hip_runtime.h>
#include <math.h>

// Problem dims (fixed by reference)
#define BATCH 2048
#define GIN 128
#define GH 128
#define NE 8
#define XIN 512
#define UU 512

typedef __attribute__((ext_vector_type(8))) short short8;   // 8 bf16 in 4 VGPRs
typedef __attribute__((ext_vector_type(4))) float f32x4;

#define AS1 __attribute__((address_space(1)))
#define AS3 __attribute__((address_space(3)))

__device__ inline unsigned short f2bf(float f) {
    unsigned u = __float_as_uint(f);
    u += 0x7fffu + ((u >> 16) & 1u);
    return (unsigned short)(u >> 16);
}

__device__ inline float elu1(float x) { return x > 0.f ? x : (expf(x) - 1.f); }

// ---------------------------------------------------------------------------
// Fused pre-pass: blocks 0..511 run the gating MLP (4 batch rows each);
// blocks 512..7679 convert alpha pools + X fp32->bf16 (1024 elems each).
// One launch instead of two serialized ones.
// ---------------------------------------------------------------------------
__global__ __launch_bounds__(256) void pre_kernel(
    const float* __restrict__ gin, const float* __restrict__ W0, const float* __restrict__ b0,
    const float* __restrict__ W1, const float* __restrict__ b1,
    const float* __restrict__ Wo, const float* __restrict__ bo,
    float* __restrict__ g,
    const float* __restrict__ a0, const float* __restrict__ a1, const float* __restrict__ a2,
    const float* __restrict__ xv, unsigned short* __restrict__ dst)
{
    __shared__ float xs[4][128];
    __shared__ float hs[4][128];
    __shared__ float ps[2][4][128];
    __shared__ float lp[8][4][8];
    __shared__ float ls[4][8];

    const int t = threadIdx.x;

    if (blockIdx.x >= 512) {
        // ---- convert part ----
        const long long vi = ((long long)(blockIdx.x - 512) * 256 + t) * 4;
        const int sel = (int)(vi >> 21);         // 0,1,2 = alpha pools; 3 = X
        const float* src = (sel == 0) ? a0 : (sel == 1) ? a1 : (sel == 2) ? a2 : xv;
        float4 v = *(const float4*)(src + (vi & ((1 << 21) - 1)));
        union { unsigned short us[4]; uint2 u2; } p;
        p.us[0] = f2bf(v.x); p.us[1] = f2bf(v.y); p.us[2] = f2bf(v.z); p.us[3] = f2bf(v.w);
        *(uint2*)(dst + vi) = p.u2;
        return;
    }

    // ---- gating part ----
    const int c = t & 127;
    const int h = t >> 7;
    const int row0 = blockIdx.x * 4;

    ((float*)xs)[t]       = gin[row0 * GIN + t];
    ((float*)xs)[t + 256] = gin[row0 * GIN + t + 256];
    __syncthreads();

    {   // layer 0
        float acc0 = 0.f, acc1 = 0.f, acc2 = 0.f, acc3 = 0.f;
        const float* Wc = W0 + c;
        #pragma unroll 8
        for (int i = h * 64; i < h * 64 + 64; ++i) {
            float w = Wc[i * GH];
            acc0 += xs[0][i] * w; acc1 += xs[1][i] * w;
            acc2 += xs[2][i] * w; acc3 += xs[3][i] * w;
        }
        ps[h][0][c] = acc0; ps[h][1][c] = acc1; ps[h][2][c] = acc2; ps[h][3][c] = acc3;
    }
    __syncthreads();
    {
        int o = t, r = o >> 7, cc = o & 127;
        hs[r][cc] = elu1(ps[0][r][cc] + ps[1][r][cc] + b0[cc]);
        o = t + 256; r = o >> 7; cc = o & 127;
        hs[r][cc] = elu1(ps[0][r][cc] + ps[1][r][cc] + b0[cc]);
    }
    __syncthreads();

    {   // layer 1
        float acc0 = 0.f, acc1 = 0.f, acc2 = 0.f, acc3 = 0.f;
        const float* Wc = W1 + c;
        #pragma unroll 8
        for (int i = h * 64; i < h * 64 + 64; ++i) {
            float w = Wc[i * GH];
            acc0 += hs[0][i] * w; acc1 += hs[1][i] * w;
            acc2 += hs[2][i] * w; acc3 += hs[3][i] * w;
        }
        ps[h][0][c] = acc0; ps[h][1][c] = acc1; ps[h][2][c] = acc2; ps[h][3][c] = acc3;
    }
    __syncthreads();
    {
        int o = t, r = o >> 7, cc = o & 127;
        xs[r][cc] = elu1(ps[0][r][cc] + ps[1][r][cc] + b1[cc]);
        o = t + 256; r = o >> 7; cc = o & 127;
        xs[r][cc] = elu1(ps[0][r][cc] + ps[1][r][cc] + b1[cc]);
    }
    __syncthreads();

    {   // output layer, 8-way k-split
        const int e = t & 7, r = (t >> 3) & 3, q = t >> 5;
        float s = 0.f;
        #pragma unroll
        for (int i = q * 16; i < q * 16 + 16; ++i) s += xs[r][i] * Wo[i * NE + e];
        lp[q][r][e] = s;
    }
    __syncthreads();
    if (t < 32) {
        const int r = t >> 3, e = t & 7;
        float s = bo[e];
        #pragma unroll
        for (int q = 0; q < 8; ++q) s += lp[q][r][e];
        ls[r][e] = s;
    }
    __syncthreads();
    if (t < 4) {
        float mx = ls[t][0];
        #pragma unroll
        for (int e = 1; e < 8; ++e) mx = fmaxf(mx, ls[t][e]);
        float s = 0.f, ex[8];
        #pragma unroll
        for (int e = 0; e < 8; ++e) { ex[e] = expf(ls[t][e] - mx); s += ex[e]; }
        float inv = 1.f / s;
        #pragma unroll
        for (int e = 0; e < 8; ++e) g[(row0 + t) * NE + e] = ex[e] * inv;
    }
}

// ---------------------------------------------------------------------------
// One fused MoE layer, B-direct-from-global edition.
//  - Block tile 64(M) x 32(N), all 8 experts, BK=32, 16 K-steps.
//  - A: double-buffered LDS (2 x 4 KB) via global_load_lds, swizzled
//    both-sides (byte ^= ((row>>1)&3)<<4).
//  - B: NO LDS. Per-lane global_load_dwordx4 directly into MFMA B-frag regs
//    (layout [e][n][k]: lane reads Bw[row=e*512+n0+j*16+fr][k0 + (lane>>4)*8],
//    16B contiguous). Double-buffered in registers, prefetched 1 step ahead.
//    LDS reads/wave-step drop 8 -> 4 (the r2 structure was ds_read-bound:
//    2048 b128 x 12cy = 10.2us/layer/CU vs 4.1us MFMA floor).
//  - Expert-split waves: wave w computes the full 64x32 tile for experts
//    {2w,2w+1}; cross-wave sum in epilogue via dedicated red[] LDS.
// Grid 512 (n-major: same-n blocks -> same XCD -> B-tile L2 reuse).
// LDS: 8(A) + 32(red) + 3 = 43 KB -> 2 blocks/CU at grid 512.
// ---------------------------------------------------------------------------
__global__ __launch_bounds__(256) void moe_layer_kernel(
    const unsigned short* __restrict__ A,
    const unsigned short* __restrict__ Bw,
    const float* __restrict__ g,
    const float* __restrict__ beta,
    unsigned short* __restrict__ Xnext,
    float* __restrict__ out, int last)
{
    constexpr int K = XIN;
    __shared__ unsigned short As[2][64 * 32];   // 2 x 4 KB
    __shared__ float red[4][64][32];            // 32 KB
    __shared__ float gs[64][8];                 // 2 KB
    __shared__ float bt[8][32];                 // 1 KB

    const int t = threadIdx.x;
    const int bid = blockIdx.x;
    const int n0 = (bid & 15) * 32;
    const int m0 = (bid >> 4) * 64;
    const int wave = t >> 6, lane = t & 63;
    const int e0 = 2 * wave;

    ((float2*)gs)[t] = ((const float2*)(g + (size_t)m0 * NE))[t];
    bt[t >> 5][t & 31] = beta[(t >> 5) * UU + n0 + (t & 31)];

    f32x4 acc[2][4][2] = {};   // [expert-in-pair][m-frag][n-frag]

    // ---- A staging source (pre-swizzled; linear LDS dest) ----
    const int slot = t & 3;                 // 16B slot within 64B LDS row
    const int arow = t >> 2;                // LDS row this thread fills
    const int acol = ((slot ^ ((arow >> 1) & 3)) * 8);
    const unsigned short* a_src = A + (size_t)(m0 + arow) * K + acol;

    // ---- B per-lane direct sources (4 frag rows per wave) ----
    const int fr = lane & 15;
    const int kq = (lane >> 4) * 8;         // k sub-offset within BK=32
    const unsigned short* b_ptr[2][2];
    #pragma unroll
    for (int ep = 0; ep < 2; ++ep)
        #pragma unroll
        for (int j = 0; j < 2; ++j)
            b_ptr[ep][j] = Bw + ((size_t)(e0 + ep) * UU + n0 + j * 16 + fr) * K + kq;

#define STAGE_A(bi, ki)                                                      \
    __builtin_amdgcn_global_load_lds(                                        \
        (const AS1 void*)(a_src + (ki)),                                     \
        (AS3 void*)(&As[bi][t * 8]), 16, 0, 0)

#define LOADB(dst, ki)                                                       \
    do {                                                                     \
        dst[0] = *(const short8*)(b_ptr[0][0] + (ki));                       \
        dst[1] = *(const short8*)(b_ptr[0][1] + (ki));                       \
        dst[2] = *(const short8*)(b_ptr[1][0] + (ki));                       \
        dst[3] = *(const short8*)(b_ptr[1][1] + (ki));                       \
    } while (0)

#define COMPUTE(bi, bf)                                                      \
    do {                                                                     \
        const int fkb_ = (lane >> 4) * 16;                                   \
        const char* Ab_ = (const char*)(&As[bi][0]);                         \
        short8 af_[4];                                                       \
        _Pragma("unroll")                                                    \
        for (int i = 0; i < 4; ++i) {                                        \
            const int row_ = fr + i * 16;                                    \
            af_[i] = *(const short8*)(Ab_ +                                  \
                     ((row_ * 64 + fkb_) ^ (((row_ >> 1) & 3) << 4)));       \
        }                                                                    \
        _Pragma("unroll")                                                    \
        for (int ep = 0; ep < 2; ++ep)                                       \
            _Pragma("unroll")                                                \
            for (int i = 0; i < 4; ++i)                                      \
                _Pragma("unroll")                                            \
                for (int j = 0; j < 2; ++j)                                  \
                    acc[ep][i][j] = __builtin_amdgcn_mfma_f32_16x16x32_bf16( \
                        af_[i], bf[ep * 2 + j], acc[ep][i][j], 0, 0, 0);     \
    } while (0)

    short8 bb0[4], bb1[4];

    // prologue: tile 0 (A -> LDS buf0, B -> bb0)
    STAGE_A(0, 0);
    LOADB(bb0, 0);
    __syncthreads();

    // main loop, fully unrolled (static buffer indices)
    #pragma unroll
    for (int s = 0; s < 16; ++s) {
        if (s < 15) {
            STAGE_A((s + 1) & 1, (s + 1) * 32);
            if (s & 1) LOADB(bb0, (s + 1) * 32);
            else       LOADB(bb1, (s + 1) * 32);
        }
        if (s & 1) COMPUTE(1, bb1);
        else       COMPUTE(0, bb0);
        __syncthreads();
    }

    // ---- epilogue: per-wave g/beta blend, cross-wave sum via LDS ----
    const int cl = lane & 15, rq = lane >> 4;
    #pragma unroll
    for (int i = 0; i < 4; ++i)
        #pragma unroll
        for (int j = 0; j < 2; ++j)
            #pragma unroll
            for (int r = 0; r < 4; ++r) {
                const int rl = i * 16 + rq * 4 + r;
                const int co = j * 16 + cl;
                const float v =
                    gs[rl][e0]     * (acc[0][i][j][r] + bt[e0][co]) +
                    gs[rl][e0 + 1] * (acc[1][i][j][r] + bt[e0 + 1][co]);
                red[wave][rl][co] = v;
            }
    __syncthreads();

    {
        const int rl = t >> 2;
        const int c0 = (t & 3) * 8;
        float v[8];
        #pragma unroll
        for (int u = 0; u < 8; ++u)
            v[u] = red[0][rl][c0 + u] + red[1][rl][c0 + u] +
                   red[2][rl][c0 + u] + red[3][rl][c0 + u];
        if (last) {
            float4 o0 = {v[0], v[1], v[2], v[3]};
            float4 o1 = {v[4], v[5], v[6], v[7]};
            float* op = out + (size_t)(m0 + rl) * UU + n0 + c0;
            *(float4*)op = o0;
            *(float4*)(op + 4) = o1;
        } else {
            union { unsigned short us[8]; short8 s8; } p;
            #pragma unroll
            for (int u = 0; u < 8; ++u) p.us[u] = f2bf(elu1(v[u]));
            *(short8*)(Xnext + (size_t)(m0 + rl) * UU + n0 + c0) = p.s8;
        }
    }
#undef STAGE_A
#undef LOADB
#undef COMPUTE
}

// ---------------------------------------------------------------------------
extern "C" void kernel_launch(void* const* d_in, const int* in_sizes, int n_in,
                              void* d_out, int out_size, void* d_ws, size_t ws_size,
                              hipStream_t stream)
{
    (void)in_sizes; (void)n_in; (void)out_size; (void)ws_size;
    const float* gin = (const float*)d_in[0];
    const float* xin = (const float*)d_in[1];
    const float* W0  = (const float*)d_in[2];
    const float* b0  = (const float*)d_in[3];
    const float* W1  = (const float*)d_in[4];
    const float* b1  = (const float*)d_in[5];
    const float* Wo  = (const float*)d_in[6];
    const float* bo  = (const float*)d_in[7];
    const float* alpha[3] = {(const float*)d_in[8],  (const float*)d_in[10], (const float*)d_in[12]};
    const float* beta[3]  = {(const float*)d_in[9],  (const float*)d_in[11], (const float*)d_in[13]};
    float* out = (float*)d_out;

    // ws layout (~16.8 MB total)
    char* ws = (char*)d_ws;
    float* g = (float*)ws;                                   // 64 KB
    size_t off = 65536;
    unsigned short* ab = (unsigned short*)(ws + off);        // 12.58 MB
    off += (size_t)3 * (1 << 21) * 2;
    unsigned short* Xb0 = (unsigned short*)(ws + off);       // 2.1 MB (contiguous after ab)
    off += (size_t)BATCH * XIN * 2;
    unsigned short* Xb1 = (unsigned short*)(ws + off);       // 2.1 MB
    off += (size_t)BATCH * XIN * 2;

    // fused gating + convert: 512 gating blocks + 7168 convert blocks
    pre_kernel<<<512 + 7168, 256, 0, stream>>>(
        gin, W0, b0, W1, b1, Wo, bo, g,
        alpha[0], alpha[1], alpha[2], xin, ab);

    // ping-pong X buffers
    unsigned short* Xsrc = Xb0;
    unsigned short* Xdst = Xb1;
    for (int l = 0; l < 3; ++l) {
        moe_layer_kernel<<<512, 256, 0, stream>>>(
            Xsrc, ab + (size_t)l * (1 << 21), g, beta[l], Xdst, out, l == 2 ? 1 : 0);
        unsigned short* tmp = Xsrc; Xsrc = Xdst; Xdst = tmp;
    }
}

// Round 5
// 160.350 us; speedup vs baseline: 1.0139x; 1.0139x over previous
//
#include <hip/hip_runtime.h>
#include <math.h>

// Problem dims (fixed by reference)
#define BATCH 2048
#define GIN 128
#define GH 128
#define NE 8
#define XIN 512
#define UU 512

typedef __attribute__((ext_vector_type(8))) short short8;   // 8 bf16 in 4 VGPRs
typedef __attribute__((ext_vector_type(4))) float f32x4;

#define AS1 __attribute__((address_space(1)))
#define AS3 __attribute__((address_space(3)))

__device__ inline unsigned short f2bf(float f) {
    unsigned u = __float_as_uint(f);
    u += 0x7fffu + ((u >> 16) & 1u);
    return (unsigned short)(u >> 16);
}

__device__ inline float elu1(float x) { return x > 0.f ? x : (expf(x) - 1.f); }

// ---------------------------------------------------------------------------
// Fused pre-pass: blocks 0..511 run the gating MLP (4 batch rows each);
// blocks 512..7679 convert alpha pools + X fp32->bf16 (1024 elems each).
// ---------------------------------------------------------------------------
__global__ __launch_bounds__(256) void pre_kernel(
    const float* __restrict__ gin, const float* __restrict__ W0, const float* __restrict__ b0,
    const float* __restrict__ W1, const float* __restrict__ b1,
    const float* __restrict__ Wo, const float* __restrict__ bo,
    float* __restrict__ g,
    const float* __restrict__ a0, const float* __restrict__ a1, const float* __restrict__ a2,
    const float* __restrict__ xv, unsigned short* __restrict__ dst)
{
    __shared__ float xs[4][128];
    __shared__ float hs[4][128];
    __shared__ float ps[2][4][128];
    __shared__ float lp[8][4][8];
    __shared__ float ls[4][8];

    const int t = threadIdx.x;

    if (blockIdx.x >= 512) {
        // ---- convert part ----
        const long long vi = ((long long)(blockIdx.x - 512) * 256 + t) * 4;
        const int sel = (int)(vi >> 21);         // 0,1,2 = alpha pools; 3 = X
        const float* src = (sel == 0) ? a0 : (sel == 1) ? a1 : (sel == 2) ? a2 : xv;
        float4 v = *(const float4*)(src + (vi & ((1 << 21) - 1)));
        union { unsigned short us[4]; uint2 u2; } p;
        p.us[0] = f2bf(v.x); p.us[1] = f2bf(v.y); p.us[2] = f2bf(v.z); p.us[3] = f2bf(v.w);
        *(uint2*)(dst + vi) = p.u2;
        return;
    }

    // ---- gating part ----
    const int c = t & 127;
    const int h = t >> 7;
    const int row0 = blockIdx.x * 4;

    ((float*)xs)[t]       = gin[row0 * GIN + t];
    ((float*)xs)[t + 256] = gin[row0 * GIN + t + 256];
    __syncthreads();

    {   // layer 0
        float acc0 = 0.f, acc1 = 0.f, acc2 = 0.f, acc3 = 0.f;
        const float* Wc = W0 + c;
        #pragma unroll 8
        for (int i = h * 64; i < h * 64 + 64; ++i) {
            float w = Wc[i * GH];
            acc0 += xs[0][i] * w; acc1 += xs[1][i] * w;
            acc2 += xs[2][i] * w; acc3 += xs[3][i] * w;
        }
        ps[h][0][c] = acc0; ps[h][1][c] = acc1; ps[h][2][c] = acc2; ps[h][3][c] = acc3;
    }
    __syncthreads();
    {
        int o = t, r = o >> 7, cc = o & 127;
        hs[r][cc] = elu1(ps[0][r][cc] + ps[1][r][cc] + b0[cc]);
        o = t + 256; r = o >> 7; cc = o & 127;
        hs[r][cc] = elu1(ps[0][r][cc] + ps[1][r][cc] + b0[cc]);
    }
    __syncthreads();

    {   // layer 1
        float acc0 = 0.f, acc1 = 0.f, acc2 = 0.f, acc3 = 0.f;
        const float* Wc = W1 + c;
        #pragma unroll 8
        for (int i = h * 64; i < h * 64 + 64; ++i) {
            float w = Wc[i * GH];
            acc0 += hs[0][i] * w; acc1 += hs[1][i] * w;
            acc2 += hs[2][i] * w; acc3 += hs[3][i] * w;
        }
        ps[h][0][c] = acc0; ps[h][1][c] = acc1; ps[h][2][c] = acc2; ps[h][3][c] = acc3;
    }
    __syncthreads();
    {
        int o = t, r = o >> 7, cc = o & 127;
        xs[r][cc] = elu1(ps[0][r][cc] + ps[1][r][cc] + b1[cc]);
        o = t + 256; r = o >> 7; cc = o & 127;
        xs[r][cc] = elu1(ps[0][r][cc] + ps[1][r][cc] + b1[cc]);
    }
    __syncthreads();

    {   // output layer, 8-way k-split
        const int e = t & 7, r = (t >> 3) & 3, q = t >> 5;
        float s = 0.f;
        #pragma unroll
        for (int i = q * 16; i < q * 16 + 16; ++i) s += xs[r][i] * Wo[i * NE + e];
        lp[q][r][e] = s;
    }
    __syncthreads();
    if (t < 32) {
        const int r = t >> 3, e = t & 7;
        float s = bo[e];
        #pragma unroll
        for (int q = 0; q < 8; ++q) s += lp[q][r][e];
        ls[r][e] = s;
    }
    __syncthreads();
    if (t < 4) {
        float mx = ls[t][0];
        #pragma unroll
        for (int e = 1; e < 8; ++e) mx = fmaxf(mx, ls[t][e]);
        float s = 0.f, ex[8];
        #pragma unroll
        for (int e = 0; e < 8; ++e) { ex[e] = expf(ls[t][e] - mx); s += ex[e]; }
        float inv = 1.f / s;
        #pragma unroll
        for (int e = 0; e < 8; ++e) g[(row0 + t) * NE + e] = ex[e] * inv;
    }
}

// ---------------------------------------------------------------------------
// One fused MoE layer — T3+T4 edition (single variable changed vs r4):
//  - SAME geometry as r4: 64Mx32N tile, 8 experts, BK=32, 16 steps, B-direct.
//  - NEW sync structure: triple-buffered A (LDS) + triple-slot B (regs),
//    prefetch distance 2, counted s_waitcnt vmcnt(5) + RAW s_barrier.
//    Never vmcnt(0) in the steady loop (the r1/r2/r4 __syncthreads drained
//    every prefetch -> ~90% stall; T4/m218 mechanism).
//    Wait math (5 VM ops/step: 1 A-lds + 4 B-dwordx4, in-order):
//    after issuing tile s+2, outstanding = 10; vmcnt(5) => tile s+1 landed.
//    Buffer safety: s, s+1, s+2 distinct mod 3; stage of s+2 issued after
//    the end-of-step-(s-1) barrier that retired all reads of that buffer.
// LDS: 12(A) + 32(red) + 3 = 47 KB. Grid 512 (2 blocks/CU).
// ---------------------------------------------------------------------------
__global__ __launch_bounds__(256) void moe_layer_kernel(
    const unsigned short* __restrict__ A,
    const unsigned short* __restrict__ Bw,
    const float* __restrict__ g,
    const float* __restrict__ beta,
    unsigned short* __restrict__ Xnext,
    float* __restrict__ out, int last)
{
    constexpr int K = XIN;
    __shared__ unsigned short As[3][64 * 32];   // 3 x 4 KB
    __shared__ float red[4][64][32];            // 32 KB
    __shared__ float gs[64][8];                 // 2 KB
    __shared__ float bt[8][32];                 // 1 KB

    const int t = threadIdx.x;
    const int bid = blockIdx.x;
    const int n0 = (bid & 15) * 32;             // bid%8 fixed per n0 pair -> B L2-resident per XCD
    const int m0 = (bid >> 4) * 64;
    const int wave = t >> 6, lane = t & 63;
    const int e0 = 2 * wave;

    ((float2*)gs)[t] = ((const float2*)(g + (size_t)m0 * NE))[t];
    bt[t >> 5][t & 31] = beta[(t >> 5) * UU + n0 + (t & 31)];

    f32x4 acc[2][4][2] = {};   // [expert-in-pair][m-frag][n-frag]

    // ---- A staging source (pre-swizzled; linear LDS dest) ----
    const int slot = t & 3;                 // 16B slot within 64B LDS row
    const int arow = t >> 2;                // LDS row this thread fills
    const int acol = ((slot ^ ((arow >> 1) & 3)) * 8);
    const unsigned short* a_src = A + (size_t)(m0 + arow) * K + acol;

    // ---- B per-lane direct sources (4 frag rows per wave) ----
    const int fr = lane & 15;
    const int kq = (lane >> 4) * 8;         // k sub-offset within BK=32
    const unsigned short* b_ptr[2][2];
    #pragma unroll
    for (int ep = 0; ep < 2; ++ep)
        #pragma unroll
        for (int j = 0; j < 2; ++j)
            b_ptr[ep][j] = Bw + ((size_t)(e0 + ep) * UU + n0 + j * 16 + fr) * K + kq;

#define STAGE_A(bi, ki)                                                      \
    __builtin_amdgcn_global_load_lds(                                        \
        (const AS1 void*)(a_src + (ki)),                                     \
        (AS3 void*)(&As[bi][t * 8]), 16, 0, 0)

#define LOADB(dst, ki)                                                       \
    do {                                                                     \
        dst[0] = *(const short8*)(b_ptr[0][0] + (ki));                       \
        dst[1] = *(const short8*)(b_ptr[0][1] + (ki));                       \
        dst[2] = *(const short8*)(b_ptr[1][0] + (ki));                       \
        dst[3] = *(const short8*)(b_ptr[1][1] + (ki));                       \
    } while (0)

#define COMPUTE(bi, bf)                                                      \
    do {                                                                     \
        const int fkb_ = (lane >> 4) * 16;                                   \
        const char* Ab_ = (const char*)(&As[bi][0]);                         \
        short8 af_[4];                                                       \
        _Pragma("unroll")                                                    \
        for (int i = 0; i < 4; ++i) {                                        \
            const int row_ = fr + i * 16;                                    \
            af_[i] = *(const short8*)(Ab_ +                                  \
                     ((row_ * 64 + fkb_) ^ (((row_ >> 1) & 3) << 4)));       \
        }                                                                    \
        _Pragma("unroll")                                                    \
        for (int ep = 0; ep < 2; ++ep)                                       \
            _Pragma("unroll")                                                \
            for (int i = 0; i < 4; ++i)                                      \
                _Pragma("unroll")                                            \
                for (int j = 0; j < 2; ++j)                                  \
                    acc[ep][i][j] = __builtin_amdgcn_mfma_f32_16x16x32_bf16( \
                        af_[i], bf[ep * 2 + j], acc[ep][i][j], 0, 0, 0);     \
    } while (0)

    short8 bb0[4], bb1[4], bb2[4];

    // prologue: tiles 0 and 1 in flight (10 VM ops); wait tile 0 (5 newer)
    STAGE_A(0, 0);  LOADB(bb0, 0);
    STAGE_A(1, 32); LOADB(bb1, 32);
    asm volatile("s_waitcnt vmcnt(5)" ::: "memory");
    __builtin_amdgcn_s_barrier();

    // steady loop: compute(s) -> issue(s+2) -> wait tile s+1 -> barrier
    #pragma unroll
    for (int s = 0; s < 16; ++s) {
        const int cur = s % 3;
        if (cur == 0)      COMPUTE(0, bb0);
        else if (cur == 1) COMPUTE(1, bb1);
        else               COMPUTE(2, bb2);

        if (s + 2 < 16) {
            const int pre = (s + 2) % 3;
            STAGE_A(pre, (s + 2) * 32);
            if (pre == 0)      LOADB(bb0, (s + 2) * 32);
            else if (pre == 1) LOADB(bb1, (s + 2) * 32);
            else               LOADB(bb2, (s + 2) * 32);
        }
        if (s < 15) {
            if (s + 2 < 16) asm volatile("s_waitcnt vmcnt(5)" ::: "memory");
            else            asm volatile("s_waitcnt vmcnt(0)" ::: "memory");
            __builtin_amdgcn_s_barrier();
        }
    }

    // ---- epilogue: per-wave g/beta blend, cross-wave sum via LDS ----
    const int cl = lane & 15, rq = lane >> 4;
    #pragma unroll
    for (int i = 0; i < 4; ++i)
        #pragma unroll
        for (int j = 0; j < 2; ++j)
            #pragma unroll
            for (int r = 0; r < 4; ++r) {
                const int rl = i * 16 + rq * 4 + r;
                const int co = j * 16 + cl;
                const float v =
                    gs[rl][e0]     * (acc[0][i][j][r] + bt[e0][co]) +
                    gs[rl][e0 + 1] * (acc[1][i][j][r] + bt[e0 + 1][co]);
                red[wave][rl][co] = v;
            }
    __syncthreads();

    {
        const int rl = t >> 2;
        const int c0 = (t & 3) * 8;
        float v[8];
        #pragma unroll
        for (int u = 0; u < 8; ++u)
            v[u] = red[0][rl][c0 + u] + red[1][rl][c0 + u] +
                   red[2][rl][c0 + u] + red[3][rl][c0 + u];
        if (last) {
            float4 o0 = {v[0], v[1], v[2], v[3]};
            float4 o1 = {v[4], v[5], v[6], v[7]};
            float* op = out + (size_t)(m0 + rl) * UU + n0 + c0;
            *(float4*)op = o0;
            *(float4*)(op + 4) = o1;
        } else {
            union { unsigned short us[8]; short8 s8; } p;
            #pragma unroll
            for (int u = 0; u < 8; ++u) p.us[u] = f2bf(elu1(v[u]));
            *(short8*)(Xnext + (size_t)(m0 + rl) * UU + n0 + c0) = p.s8;
        }
    }
#undef STAGE_A
#undef LOADB
#undef COMPUTE
}

// ---------------------------------------------------------------------------
extern "C" void kernel_launch(void* const* d_in, const int* in_sizes, int n_in,
                              void* d_out, int out_size, void* d_ws, size_t ws_size,
                              hipStream_t stream)
{
    (void)in_sizes; (void)n_in; (void)out_size; (void)ws_size;
    const float* gin = (const float*)d_in[0];
    const float* xin = (const float*)d_in[1];
    const float* W0  = (const float*)d_in[2];
    const float* b0  = (const float*)d_in[3];
    const float* W1  = (const float*)d_in[4];
    const float* b1  = (const float*)d_in[5];
    const float* Wo  = (const float*)d_in[6];
    const float* bo  = (const float*)d_in[7];
    const float* alpha[3] = {(const float*)d_in[8],  (const float*)d_in[10], (const float*)d_in[12]};
    const float* beta[3]  = {(const float*)d_in[9],  (const float*)d_in[11], (const float*)d_in[13]};
    float* out = (float*)d_out;

    // ws layout (~16.8 MB total)
    char* ws = (char*)d_ws;
    float* g = (float*)ws;                                   // 64 KB
    size_t off = 65536;
    unsigned short* ab = (unsigned short*)(ws + off);        // 12.58 MB
    off += (size_t)3 * (1 << 21) * 2;
    unsigned short* Xb0 = (unsigned short*)(ws + off);       // 2.1 MB (contiguous after ab)
    off += (size_t)BATCH * XIN * 2;
    unsigned short* Xb1 = (unsigned short*)(ws + off);       // 2.1 MB
    off += (size_t)BATCH * XIN * 2;

    // fused gating + convert: 512 gating blocks + 7168 convert blocks
    pre_kernel<<<512 + 7168, 256, 0, stream>>>(
        gin, W0, b0, W1, b1, Wo, bo, g,
        alpha[0], alpha[1], alpha[2], xin, ab);

    // ping-pong X buffers
    unsigned short* Xsrc = Xb0;
    unsigned short* Xdst = Xb1;
    for (int l = 0; l < 3; ++l) {
        moe_layer_kernel<<<512, 256, 0, stream>>>(
            Xsrc, ab + (size_t)l * (1 << 21), g, beta[l], Xdst, out, l == 2 ? 1 : 0);
        unsigned short* tmp = Xsrc; Xsrc = Xdst; Xdst = tmp;
    }
}